// Round 4
// baseline (1770.224 us; speedup 1.0000x reference)
//
#include <hip/hip_runtime.h>
#include <math.h>

// Problem dims (fixed by the reference file)
#define DHID 128
#define DXIN 16
#define DIN  144   // DHID + DXIN
#define G3   384   // 3*DHID
#define NLEV 16
#define SCAN_CHUNK 2048
#define KP   160   // GEMM1 K padded to mult of 32
#define AS   168   // A LDS row stride in bf16 units (336 B: 16B-aligned, 2-way banks)
#define HS   136   // H LDS row stride in bf16 units (272 B)

typedef __attribute__((ext_vector_type(8))) short short8_t;
typedef __attribute__((ext_vector_type(4))) float f32x4;

__device__ __forceinline__ float sigmoidf_(float v){ return 1.0f/(1.0f + __expf(-v)); }
__device__ __forceinline__ float tanhf_(float v){
  v = fminf(fmaxf(v,-15.f),15.f);
  float e = __expf(2.f*v);
  return (e-1.f)/(e+1.f);
}
// round-to-nearest-even fp32 -> bf16 (as ushort)
__device__ __forceinline__ unsigned short f2bf(float f){
  unsigned u = __float_as_uint(f);
  u = u + 0x7FFFu + ((u>>16)&1u);
  return (unsigned short)(u>>16);
}
__device__ __forceinline__ float bf2f(unsigned short h){
  return __uint_as_float(((unsigned)h)<<16);
}

// ---------------- zero counters / indeg / fill ----------------
__global__ void k_zero0(int* ints, int* indeg, int* fill, int N){
  int i = blockIdx.x*blockDim.x + threadIdx.x;
  int stride = gridDim.x*blockDim.x;
  if(i<256) ints[i]=0;
  for(int j=i;j<N;j+=stride){ indeg[j]=0; fill[j]=0; }
}

// ---------------- precompute h_init, t_init, gh_init, c0 ----------------
// consts (floats): [0..127]=h_init [128..255]=t_init [256..639]=gh_init(r,z,n) [640]=c0
__global__ void k_init(const float* emd_w, const float* emd_b,
                       const float* agg_w, const float* agg_b,
                       const float* w_hh, const float* b_hh,
                       const float* w1,const float* b1,const float* w2,const float* b2,
                       const float* w3,const float* b3,
                       float* consts){
  __shared__ float hl[128];
  __shared__ float z1[32];
  __shared__ float z2[32];
  int t = threadIdx.x;
  float h = emd_w[t] + emd_b[t];
  hl[t] = h; consts[t] = h;
  __syncthreads();
  float s = agg_b[t];
  for(int k=0;k<128;k++) s += agg_w[t*128+k]*hl[k];
  consts[128+t] = s;
  for(int g=t; g<G3; g+=128){
    float q = b_hh[g];
    for(int k=0;k<128;k++) q += w_hh[g*128+k]*hl[k];
    consts[256+g] = q;
  }
  if(t<32){
    float a = b1[t];
    for(int k=0;k<128;k++) a += w1[t*128+k]*hl[k];
    z1[t] = fmaxf(a,0.f);
  }
  __syncthreads();
  if(t<32){
    float a = b2[t];
    for(int k=0;k<32;k++) a += w2[t*32+k]*z1[k];
    z2[t] = fmaxf(a,0.f);
  }
  __syncthreads();
  if(t==0){
    float a = b3[0];
    for(int k=0;k<32;k++) a += w3[k]*z2[k];
    consts[640] = a;
  }
}

// ---------------- split weights into bf16 hi/lo (fp32-accurate bf16x3 path) ------
__global__ void k_wprep(const float* w_ih, const float* agg_w, const float* w1,
                        unsigned short* wih_h, unsigned short* wih_l,
                        unsigned short* agg_h, unsigned short* agg_l,
                        unsigned short* w1_h, unsigned short* w1_l){
  int i = blockIdx.x*blockDim.x + threadIdx.x;
  int stride = gridDim.x*blockDim.x;
  for(int idx=i; idx<G3*KP; idx+=stride){
    int g = idx/KP, k = idx - g*KP;
    float v = (k<DIN)? w_ih[g*DIN+k] : 0.f;
    unsigned short h = f2bf(v);
    wih_h[idx]=h; wih_l[idx]=f2bf(v-bf2f(h));
  }
  for(int idx=i; idx<DHID*DHID; idx+=stride){
    float v = agg_w[idx];
    unsigned short h=f2bf(v); agg_h[idx]=h; agg_l[idx]=f2bf(v-bf2f(h));
  }
  for(int idx=i; idx<32*DHID; idx+=stride){
    float v = w1[idx];
    unsigned short h=f2bf(v); w1_h[idx]=h; w1_l[idx]=f2bf(v-bf2f(h));
  }
}

// ---------------- node histogram by level ----------------
// ints: node_cnt@0(16) node_off@32(17) node_fill@64(16)
__global__ void k_count(const int* fl, int N, int* ints){
  __shared__ int hn[16];
  int tid = threadIdx.x;
  if(tid<16) hn[tid]=0;
  __syncthreads();
  int i = blockIdx.x*blockDim.x+tid;
  int stride = gridDim.x*blockDim.x;
  for(int j=i;j<N;j+=stride) atomicAdd(&hn[fl[j]], 1);
  __syncthreads();
  if(tid<16 && hn[tid]) atomicAdd(&ints[tid], hn[tid]);
}

__global__ void k_prefix(int* ints){
  if(threadIdx.x==0 && blockIdx.x==0){
    int o=0;
    for(int l=0;l<NLEV;l++){ ints[32+l]=o; ints[64+l]=o; o+=ints[l]; }
    ints[32+NLEV]=o;
  }
}

// Two-pass per-block counting sort of nodes by level.
__global__ void k_build(const int* fl, int N, int* ints,
                        int* node_list, int* node_rank){
  __shared__ int h[16], base[16];
  int tid = threadIdx.x;
  int nchunk = (N + gridDim.x - 1)/gridDim.x;
  int lo = blockIdx.x*nchunk;
  int hi = lo + nchunk; if(hi>N) hi=N;
  if(tid<16) h[tid]=0;
  __syncthreads();
  for(int j=lo+tid; j<hi; j+=blockDim.x) atomicAdd(&h[fl[j]],1);
  __syncthreads();
  if(tid<16){ base[tid] = h[tid] ? atomicAdd(&ints[64+tid], h[tid]) : 0; h[tid]=0; }
  __syncthreads();
  for(int j=lo+tid; j<hi; j+=blockDim.x){
    int lev = fl[j];
    int pos = base[lev] + atomicAdd(&h[lev],1);
    node_list[pos]=j;
    node_rank[j]=pos-ints[32+lev];
  }
}

// ---------------- indegree histogram over permuted node positions ----------------
__global__ void k_indeg(const int* ei, const int* fl, const int* node_rank,
                        const int* ints, int* indeg, int E){
  int i = blockIdx.x*blockDim.x+threadIdx.x;
  int stride = gridDim.x*blockDim.x;
  for(int e=i;e<E;e+=stride){
    int tg = ei[E+e];
    int p = ints[32+fl[tg]] + node_rank[tg];
    atomicAdd(&indeg[p],1);
  }
}

// ---------------- hierarchical exclusive scan of indeg -> row_ptr ----------------
__global__ void k_scan_a(const int* indeg, int* bsum, int N){
  __shared__ int ts[256];
  int b=blockIdx.x, t=threadIdx.x;
  int base=b*SCAN_CHUNK+t*8; int s=0;
  for(int j=0;j<8;j++){ int idx=base+j; if(idx<N) s+=indeg[idx]; }
  ts[t]=s; __syncthreads();
  for(int off=128;off>0;off>>=1){ if(t<off) ts[t]+=ts[t+off]; __syncthreads(); }
  if(t==0) bsum[b]=ts[0];
}
__global__ void k_scan_b(int* bsum, int nb){
  __shared__ int ls[256];
  int t=threadIdx.x;
  int v = (t<nb)? bsum[t]:0; ls[t]=v; __syncthreads();
  for(int off=1;off<256;off<<=1){
    int add = (t>=off)? ls[t-off]:0;
    __syncthreads();
    ls[t]+=add;
    __syncthreads();
  }
  if(t<nb) bsum[t] = ls[t]-v;   // exclusive
}
__global__ void k_scan_c(const int* indeg, const int* bsum, int* row_ptr, int N){
  __shared__ int ts[256];
  int b=blockIdx.x, t=threadIdx.x;
  int base=b*SCAN_CHUNK+t*8;
  int v[8]; int s=0;
  for(int j=0;j<8;j++){ int idx=base+j; v[j]=(idx<N)?indeg[idx]:0; s+=v[j]; }
  ts[t]=s; __syncthreads();
  for(int off=1;off<256;off<<=1){
    int add = (t>=off)? ts[t-off]:0;
    __syncthreads();
    ts[t]+=add;
    __syncthreads();
  }
  int excl = bsum[b] + ((t>0)? ts[t-1]:0);
  for(int j=0;j<8;j++){ int idx=base+j; if(idx<N) row_ptr[idx]=excl; excl+=v[j]; }
}

// ---------------- place edges into CSR, packing source level into bits 27+ -------
__global__ void k_place(const int* ei, const int* fl, const int* node_rank,
                        const int* ints, const int* row_ptr, int* fill,
                        int* edge_src, int E){
  int i = blockIdx.x*blockDim.x+threadIdx.x;
  int stride = gridDim.x*blockDim.x;
  for(int e=i;e<E;e+=stride){
    int s  = ei[e];
    int tg = ei[E+e];
    int p = ints[32+fl[tg]] + node_rank[tg];
    int slot = atomicAdd(&fill[p],1);
    edge_src[row_ptr[p]+slot] = s | (fl[s]<<27);
  }
}

// ---------------- out = c0 everywhere ----------------
__global__ void k_outc(float* out, const float* consts, int N){
  int i = blockIdx.x*blockDim.x+threadIdx.x;
  int stride = gridDim.x*blockDim.x;
  float c0 = consts[640];
  for(int j=i;j<N;j+=stride) out[j]=c0;
}

// ---------------- fused per-level (MFMA bf16x3): gather + GEMM1 + GRU + GEMM2 + MLP
// LDS (38912 B -> 4 blocks/CU):
//   Ahi @0      [32][AS] bf16 = 10752 B     (z1l [32][33] f32 @0, z2l @4224 alias A)
//   Alo @10752  [32][AS]      = 10752
//   Hhi @21504  [32][HS] bf16 = 8704
//   Hlo @30208  [32][HS]      = 8704
__global__ __launch_bounds__(256,3) void k_fused(
    const float* __restrict__ x, const int* __restrict__ node_list,
    const int* __restrict__ row_ptr, const int* __restrict__ indeg,
    const int* __restrict__ edge_src,
    float* __restrict__ tbuf,
    const unsigned short* __restrict__ wih_h, const unsigned short* __restrict__ wih_l,
    const unsigned short* __restrict__ agg_h, const unsigned short* __restrict__ agg_l,
    const unsigned short* __restrict__ w1_h, const unsigned short* __restrict__ w1_l,
    const float* __restrict__ b_ih, const float* __restrict__ agg_b,
    const float* __restrict__ b1, const float* __restrict__ w2,
    const float* __restrict__ b2, const float* __restrict__ w3,
    const float* __restrict__ b3,
    const float* __restrict__ consts, float* __restrict__ out,
    const int* __restrict__ ints, int l)
{
  __shared__ __align__(16) unsigned char smem[38912];
  unsigned short* Ahi = (unsigned short*)smem;
  unsigned short* Alo = (unsigned short*)(smem + 10752);
  unsigned short* Hhi = (unsigned short*)(smem + 21504);
  unsigned short* Hlo = (unsigned short*)(smem + 30208);
  float* z1l = (float*)smem;             // alias A (dead after GEMM1)
  float* z2l = (float*)(smem + 4224);

  int base = ints[32+l];
  int cnt  = ints[0+l];
  int tiles = (cnt+31)>>5;
  int tid = threadIdx.x;
  int wv = tid>>6, ln = tid&63;
  int lr = ln&15, lq = ln>>4;
  int cg = tid&7, nd = tid>>3;

  // hoisted per-lane constants (wave wv owns dims 32wv..32wv+31; c selects 16-half)
  float ghr[2],ghz[2],ghn[2],h0c[2],bir[2],biz[2],bin_[2],ab2[2];
  #pragma unroll
  for(int c=0;c<2;c++){
    int d = 32*wv + 16*c + lr;
    ghr[c]=consts[256+d]; ghz[c]=consts[384+d]; ghn[c]=consts[512+d]; h0c[c]=consts[d];
    bir[c]=b_ih[d]; biz[c]=b_ih[128+d]; bin_[c]=b_ih[256+d]; ab2[c]=agg_b[d];
  }
  float b1o = (wv<2)? b1[16*wv+lr] : 0.f;

  // t_init fragment for gather columns (dims cg*16..cg*16+15)
  f32x4 ti[4];
  {
    const f32x4* c4 = (const f32x4*)(consts+128);
    #pragma unroll
    for(int q=0;q<4;q++) ti[q]=c4[cg*4+q];
  }

  for(int tile = blockIdx.x; tile < tiles; tile += gridDim.x){
    int n0 = tile*32;

    // ---- gather msg (fp32) -> split bf16 hi/lo into A LDS [32][AS] ----
    {
      f32x4 a[4];
      #pragma unroll
      for(int q=0;q<4;q++) a[q]=(f32x4){0.f,0.f,0.f,0.f};
      int gi = n0+nd;
      if(gi<cnt){
        int p = base+gi;
        int r0 = row_ptr[p], deg = indeg[p];
        const f32x4* t4 = (const f32x4*)tbuf;
        for(int e=0;e<deg;e++){
          int pk = edge_src[r0+e];
          int fls = ((unsigned)pk)>>27;
          int s = pk & 0x07FFFFFF;
          if(fls>=1 && fls<l){
            const f32x4* srcp = t4 + ((long long)s*32 + cg*4);
            #pragma unroll
            for(int q=0;q<4;q++) a[q]+=srcp[q];
          } else {
            #pragma unroll
            for(int q=0;q<4;q++) a[q]+=ti[q];
          }
        }
      }
      short8_t hv0,hv1,lv0,lv1;
      #pragma unroll
      for(int j=0;j<8;j++){
        float v0 = a[j>>2][j&3];
        float v1 = a[2+(j>>2)][j&3];
        unsigned short h0=f2bf(v0), h1=f2bf(v1);
        hv0[j]=(short)h0; lv0[j]=(short)f2bf(v0-bf2f(h0));
        hv1[j]=(short)h1; lv1[j]=(short)f2bf(v1-bf2f(h1));
      }
      *(short8_t*)&Ahi[nd*AS+cg*16]   = hv0;
      *(short8_t*)&Ahi[nd*AS+cg*16+8] = hv1;
      *(short8_t*)&Alo[nd*AS+cg*16]   = lv0;
      *(short8_t*)&Alo[nd*AS+cg*16+8] = lv1;
    }
    // ---- x into A cols 128..143, zero pad 144..159 ----
    if(tid<32){
      int gi = n0+tid;
      f32x4 xv[4];
      if(gi<cnt){
        const f32x4* xp = (const f32x4*)(x + (long long)node_list[base+gi]*16);
        #pragma unroll
        for(int q=0;q<4;q++) xv[q]=xp[q];
      } else {
        #pragma unroll
        for(int q=0;q<4;q++) xv[q]=(f32x4){0.f,0.f,0.f,0.f};
      }
      short8_t hv0,hv1,lv0,lv1;
      #pragma unroll
      for(int j=0;j<8;j++){
        float v0 = xv[j>>2][j&3];
        float v1 = xv[2+(j>>2)][j&3];
        unsigned short h0=f2bf(v0), h1=f2bf(v1);
        hv0[j]=(short)h0; lv0[j]=(short)f2bf(v0-bf2f(h0));
        hv1[j]=(short)h1; lv1[j]=(short)f2bf(v1-bf2f(h1));
      }
      short8_t z8 = {0,0,0,0,0,0,0,0};
      *(short8_t*)&Ahi[tid*AS+128] = hv0;
      *(short8_t*)&Ahi[tid*AS+136] = hv1;
      *(short8_t*)&Alo[tid*AS+128] = lv0;
      *(short8_t*)&Alo[tid*AS+136] = lv1;
      *(short8_t*)&Ahi[tid*AS+144] = z8;
      *(short8_t*)&Ahi[tid*AS+152] = z8;
      *(short8_t*)&Alo[tid*AS+144] = z8;
      *(short8_t*)&Alo[tid*AS+152] = z8;
    }
    __syncthreads();

    // ---- GEMM1 (MFMA bf16x3): gi = W_ih @ [msg,x] + b_ih ----
    f32x4 Ar[2][2],Az[2][2],An[2][2];
    #pragma unroll
    for(int m=0;m<2;m++)
    #pragma unroll
    for(int c=0;c<2;c++){
      Ar[m][c]=(f32x4){bir[c],bir[c],bir[c],bir[c]};
      Az[m][c]=(f32x4){biz[c],biz[c],biz[c],biz[c]};
      An[m][c]=(f32x4){bin_[c],bin_[c],bin_[c],bin_[c]};
    }
    #pragma unroll
    for(int kk=0;kk<5;kk++){
      short8_t ah[2],al[2];
      #pragma unroll
      for(int m=0;m<2;m++){
        int off = (m*16+lr)*AS + kk*32 + lq*8;
        ah[m]=*(const short8_t*)&Ahi[off];
        al[m]=*(const short8_t*)&Alo[off];
      }
      #pragma unroll
      for(int c=0;c<2;c++){
        int rb = 32*wv + 16*c + lr;
        #pragma unroll
        for(int g=0;g<3;g++){
          long long ro = (long long)(g*128+rb)*KP + kk*32 + lq*8;
          short8_t bh=*(const short8_t*)&wih_h[ro];
          short8_t bl=*(const short8_t*)&wih_l[ro];
          #pragma unroll
          for(int m=0;m<2;m++){
            f32x4* A = (g==0)? &Ar[m][c] : (g==1)? &Az[m][c] : &An[m][c];
            *A = __builtin_amdgcn_mfma_f32_16x16x32_bf16(ah[m],bh,*A,0,0,0);
            *A = __builtin_amdgcn_mfma_f32_16x16x32_bf16(ah[m],bl,*A,0,0,0);
            *A = __builtin_amdgcn_mfma_f32_16x16x32_bf16(al[m],bh,*A,0,0,0);
          }
        }
      }
    }

    // ---- GRU gates in-register -> h (bf16 hi/lo) into H LDS ----
    // D layout: col(dim)=lane&15, row(node)=(lane>>4)*4+reg
    #pragma unroll
    for(int m=0;m<2;m++)
    #pragma unroll
    for(int c=0;c<2;c++){
      int d = 32*wv + 16*c + lr;
      #pragma unroll
      for(int j=0;j<4;j++){
        float r = sigmoidf_(Ar[m][c][j] + ghr[c]);
        float z = sigmoidf_(Az[m][c][j] + ghz[c]);
        float n = tanhf_(An[m][c][j] + r*ghn[c]);
        float h = (1.f-z)*n + z*h0c[c];
        int node = m*16 + lq*4 + j;
        unsigned short hb=f2bf(h);
        Hhi[node*HS + d] = hb;
        Hlo[node*HS + d] = f2bf(h - bf2f(hb));
      }
    }
    __syncthreads();

    // ---- GEMM2: t = agg_w @ h + agg_b ; MLP1 (waves 0,1): z1 = relu(w1@h+b1) ----
    f32x4 T[2][2]; f32x4 M1[2];
    #pragma unroll
    for(int m=0;m<2;m++){
      #pragma unroll
      for(int c=0;c<2;c++) T[m][c]=(f32x4){ab2[c],ab2[c],ab2[c],ab2[c]};
      M1[m]=(f32x4){b1o,b1o,b1o,b1o};
    }
    #pragma unroll
    for(int kk=0;kk<4;kk++){
      short8_t ah[2],al[2];
      #pragma unroll
      for(int m=0;m<2;m++){
        int off = (m*16+lr)*HS + kk*32 + lq*8;
        ah[m]=*(const short8_t*)&Hhi[off];
        al[m]=*(const short8_t*)&Hlo[off];
      }
      #pragma unroll
      for(int c=0;c<2;c++){
        int ro = (32*wv+16*c+lr)*DHID + kk*32 + lq*8;
        short8_t bh=*(const short8_t*)&agg_h[ro];
        short8_t bl=*(const short8_t*)&agg_l[ro];
        #pragma unroll
        for(int m=0;m<2;m++){
          T[m][c] = __builtin_amdgcn_mfma_f32_16x16x32_bf16(ah[m],bh,T[m][c],0,0,0);
          T[m][c] = __builtin_amdgcn_mfma_f32_16x16x32_bf16(ah[m],bl,T[m][c],0,0,0);
          T[m][c] = __builtin_amdgcn_mfma_f32_16x16x32_bf16(al[m],bh,T[m][c],0,0,0);
        }
      }
      if(wv<2){
        int ro = (16*wv+lr)*DHID + kk*32 + lq*8;
        short8_t bh=*(const short8_t*)&w1_h[ro];
        short8_t bl=*(const short8_t*)&w1_l[ro];
        #pragma unroll
        for(int m=0;m<2;m++){
          M1[m] = __builtin_amdgcn_mfma_f32_16x16x32_bf16(ah[m],bh,M1[m],0,0,0);
          M1[m] = __builtin_amdgcn_mfma_f32_16x16x32_bf16(ah[m],bl,M1[m],0,0,0);
          M1[m] = __builtin_amdgcn_mfma_f32_16x16x32_bf16(al[m],bh,M1[m],0,0,0);
        }
      }
    }
    // t -> tbuf (fp32, rows = original node ids)
    #pragma unroll
    for(int m=0;m<2;m++)
    #pragma unroll
    for(int j=0;j<4;j++){
      int node = m*16 + lq*4 + j;
      int gi = n0+node;
      if(gi<cnt){
        long long v = node_list[base+gi];
        #pragma unroll
        for(int c=0;c<2;c++)
          tbuf[v*128 + 32*wv+16*c+lr] = T[m][c][j];
      }
    }
    // z1 -> LDS (aliases A region; A is dead)
    if(wv<2){
      #pragma unroll
      for(int m=0;m<2;m++)
      #pragma unroll
      for(int j=0;j<4;j++){
        int node = m*16 + lq*4 + j;
        z1l[node*33 + 16*wv+lr] = fmaxf(M1[m][j],0.f);
      }
    }
    __syncthreads();

    // ---- MLP2 (fp32 VALU) ----
    {
      int i = tid>>3, jb=(tid&7)*4;
      float s[4]={b2[jb],b2[jb+1],b2[jb+2],b2[jb+3]};
      for(int k=0;k<32;k++){
        float zv = z1l[i*33+k];
        #pragma unroll
        for(int jj=0;jj<4;jj++) s[jj] += zv*w2[(jb+jj)*32+k];
      }
      #pragma unroll
      for(int jj=0;jj<4;jj++) z2l[i*33+jb+jj]=fmaxf(s[jj],0.f);
    }
    __syncthreads();
    if(tid<32){
      int gi=n0+tid;
      if(gi<cnt){
        float s=b3[0];
        for(int k=0;k<32;k++) s += z2l[tid*33+k]*w3[k];
        out[node_list[base+gi]] = s;
      }
    }
    __syncthreads();   // protect LDS before next tile
  }
}

extern "C" void kernel_launch(void* const* d_in, const int* in_sizes, int n_in,
                              void* d_out, int out_size, void* d_ws, size_t ws_size,
                              hipStream_t stream){
  const float* x     = (const float*)d_in[0];
  const int*   ei    = (const int*)  d_in[1];
  const int*   fl    = (const int*)  d_in[2];
  const float* emd_w = (const float*)d_in[4];
  const float* emd_b = (const float*)d_in[5];
  const float* agg_w = (const float*)d_in[6];
  const float* agg_b = (const float*)d_in[7];
  const float* w_ih  = (const float*)d_in[8];
  const float* w_hh  = (const float*)d_in[9];
  const float* b_ih  = (const float*)d_in[10];
  const float* b_hh  = (const float*)d_in[11];
  const float* w1    = (const float*)d_in[12];
  const float* b1    = (const float*)d_in[13];
  const float* w2    = (const float*)d_in[14];
  const float* b2    = (const float*)d_in[15];
  const float* w3    = (const float*)d_in[16];
  const float* b3    = (const float*)d_in[17];
  float* out = (float*)d_out;

  int N = in_sizes[2];
  int E = in_sizes[1]/2;
  int nb = (N + SCAN_CHUNK - 1)/SCAN_CHUNK;

  char* ws = (char*)d_ws;
  float* consts   = (float*)ws;                    // 4 KiB
  int*   ints     = (int*)(ws + 4096);             // 4 KiB
  int*   node_list= (int*)(ws + 8192);
  int*   node_rank= node_list + N;
  int*   indeg    = node_rank + N;
  int*   row_ptr  = indeg + N;
  int*   fill     = row_ptr + N;
  int*   bsum     = fill + N;                      // 1024 block sums
  int*   edge_src = bsum + 1024;                   // E ints (level packed in bits 27+)
  size_t off0 = 8192 + ((size_t)5*N + 1024 + (size_t)E)*4;
  off0 = (off0 + 255) & ~(size_t)255;
  unsigned short* wih_h = (unsigned short*)(ws + off0);       // 384*160
  unsigned short* wih_l = wih_h + G3*KP;
  unsigned short* agg_h = wih_l + G3*KP;                      // 128*128
  unsigned short* agg_l = agg_h + DHID*DHID;
  unsigned short* w1_h  = agg_l + DHID*DHID;                  // 32*128
  unsigned short* w1_l  = w1_h + 32*DHID;
  size_t off1 = off0 + (size_t)(2*G3*KP + 2*DHID*DHID + 2*32*DHID)*2;
  off1 = (off1 + 255) & ~(size_t)255;
  float* tbuf = (float*)(ws + off1);               // N*128 floats, never pre-initialized
  size_t need = off1 + (size_t)N*128*4;
  if(ws_size < need) return;

  k_zero0  <<<512,256,0,stream>>>(ints, indeg, fill, N);
  k_init   <<<1,128,0,stream>>>(emd_w,emd_b,agg_w,agg_b,w_hh,b_hh,w1,b1,w2,b2,w3,b3,consts);
  k_wprep  <<<256,256,0,stream>>>(w_ih,agg_w,w1,wih_h,wih_l,agg_h,agg_l,w1_h,w1_l);
  k_count  <<<512,256,0,stream>>>(fl,N,ints);
  k_prefix <<<1,1,0,stream>>>(ints);
  k_build  <<<512,256,0,stream>>>(fl,N,ints,node_list,node_rank);
  k_indeg  <<<1024,256,0,stream>>>(ei,fl,node_rank,ints,indeg,E);
  k_scan_a <<<nb,256,0,stream>>>(indeg,bsum,N);
  k_scan_b <<<1,256,0,stream>>>(bsum,nb);
  k_scan_c <<<nb,256,0,stream>>>(indeg,bsum,row_ptr,N);
  k_place  <<<1024,256,0,stream>>>(ei,fl,node_rank,ints,row_ptr,fill,edge_src,E);
  k_outc   <<<512,256,0,stream>>>(out,consts,N);
  for(int l=1;l<NLEV;l++){
    k_fused<<<512,256,0,stream>>>(x,node_list,row_ptr,indeg,edge_src,tbuf,
                                  wih_h,wih_l,agg_h,agg_l,w1_h,w1_l,
                                  b_ih,agg_b,b1,w2,b2,w3,b3,consts,out,ints,l);
  }
}

// Round 5
// 1186.892 us; speedup vs baseline: 1.4915x; 1.4915x over previous
//
#include <hip/hip_runtime.h>
#include <math.h>

// Problem dims (fixed by the reference file)
#define DHID 128
#define DXIN 16
#define DIN  144   // DHID + DXIN
#define G3   384   // 3*DHID
#define NLEV 16
#define SCAN_CHUNK 2048
#define KP   160   // GEMM1 K padded to mult of 32
#define AS   168   // A LDS row stride in bf16 units (336 B = 21*16, 2-way banks)
#define HS   136   // H LDS row stride in bf16 units (272 B = 17*16, 2-way banks)
#define GRID 256
#define BLK  512

typedef __attribute__((ext_vector_type(8))) short short8_t;
typedef __attribute__((ext_vector_type(4))) float f32x4;

__device__ __forceinline__ float sigmoidf_(float v){ return 1.0f/(1.0f + __expf(-v)); }
__device__ __forceinline__ float tanhf_(float v){
  v = fminf(fmaxf(v,-15.f),15.f);
  float e = __expf(2.f*v);
  return (e-1.f)/(e+1.f);
}
__device__ __forceinline__ unsigned short f2bf(float f){
  unsigned u = __float_as_uint(f);
  u = u + 0x7FFFu + ((u>>16)&1u);
  return (unsigned short)(u>>16);
}
__device__ __forceinline__ float bf2f(unsigned short h){
  return __uint_as_float(((unsigned)h)<<16);
}

// device-scope sense barrier (all blocks co-resident: 1 block/CU by VGPR cap)
__device__ __forceinline__ void grid_barrier(int* cnt, int* sense, int nb, int p){
  __syncthreads();
  if(threadIdx.x==0){
    __threadfence();
    int a = __hip_atomic_fetch_add(cnt, 1, __ATOMIC_ACQ_REL, __HIP_MEMORY_SCOPE_AGENT);
    if(a == nb-1){
      __hip_atomic_store(cnt, 0, __ATOMIC_RELAXED, __HIP_MEMORY_SCOPE_AGENT);
      __hip_atomic_store(sense, p, __ATOMIC_RELEASE, __HIP_MEMORY_SCOPE_AGENT);
    } else {
      while(__hip_atomic_load(sense, __ATOMIC_ACQUIRE, __HIP_MEMORY_SCOPE_AGENT) < p){
        __builtin_amdgcn_s_sleep(8);
      }
    }
    __threadfence();
  }
  __syncthreads();
}

// ---------------- zero counters / indeg / fill ----------------
__global__ void k_zero0(int* ints, int* indeg, int* fill, int N){
  int i = blockIdx.x*blockDim.x + threadIdx.x;
  int stride = gridDim.x*blockDim.x;
  if(i<256) ints[i]=0;
  for(int j=i;j<N;j+=stride){ indeg[j]=0; fill[j]=0; }
}

// ---------------- precompute h_init, t_init, gh_init, c0 ----------------
// consts (floats): [0..127]=h_init [128..255]=t_init [256..639]=gh(r,z,n) [640]=c0
__global__ void k_init(const float* emd_w, const float* emd_b,
                       const float* agg_w, const float* agg_b,
                       const float* w_hh, const float* b_hh,
                       const float* w1,const float* b1,const float* w2,const float* b2,
                       const float* w3,const float* b3,
                       float* consts){
  __shared__ float hl[128];
  __shared__ float z1[32];
  __shared__ float z2[32];
  int t = threadIdx.x;
  float h = emd_w[t] + emd_b[t];
  hl[t] = h; consts[t] = h;
  __syncthreads();
  float s = agg_b[t];
  for(int k=0;k<128;k++) s += agg_w[t*128+k]*hl[k];
  consts[128+t] = s;
  for(int g=t; g<G3; g+=128){
    float q = b_hh[g];
    for(int k=0;k<128;k++) q += w_hh[g*128+k]*hl[k];
    consts[256+g] = q;
  }
  if(t<32){
    float a = b1[t];
    for(int k=0;k<128;k++) a += w1[t*128+k]*hl[k];
    z1[t] = fmaxf(a,0.f);
  }
  __syncthreads();
  if(t<32){
    float a = b2[t];
    for(int k=0;k<32;k++) a += w2[t*32+k]*z1[k];
    z2[t] = fmaxf(a,0.f);
  }
  __syncthreads();
  if(t==0){
    float a = b3[0];
    for(int k=0;k<32;k++) a += w3[k]*z2[k];
    consts[640] = a;
  }
}

// ---------------- split weights into bf16 hi/lo ----------------
__global__ void k_wprep(const float* w_ih, const float* agg_w,
                        unsigned short* wih_h, unsigned short* wih_l,
                        unsigned short* agg_h, unsigned short* agg_l){
  int i = blockIdx.x*blockDim.x + threadIdx.x;
  int stride = gridDim.x*blockDim.x;
  for(int idx=i; idx<G3*KP; idx+=stride){
    int g = idx/KP, k = idx - g*KP;
    float v = (k<DIN)? w_ih[g*DIN+k] : 0.f;
    unsigned short h = f2bf(v);
    wih_h[idx]=h; wih_l[idx]=f2bf(v-bf2f(h));
  }
  for(int idx=i; idx<DHID*DHID; idx+=stride){
    float v = agg_w[idx];
    unsigned short h=f2bf(v); agg_h[idx]=h; agg_l[idx]=f2bf(v-bf2f(h));
  }
}

// ---------------- node histogram by level ----------------
// ints: node_cnt@0(16) node_off@32(17) node_fill@64(16) barrier@200,201
__global__ void k_count(const int* fl, int N, int* ints){
  __shared__ int hn[16];
  int tid = threadIdx.x;
  if(tid<16) hn[tid]=0;
  __syncthreads();
  int i = blockIdx.x*blockDim.x+tid;
  int stride = gridDim.x*blockDim.x;
  for(int j=i;j<N;j+=stride) atomicAdd(&hn[fl[j]], 1);
  __syncthreads();
  if(tid<16 && hn[tid]) atomicAdd(&ints[tid], hn[tid]);
}

__global__ void k_prefix(int* ints){
  if(threadIdx.x==0 && blockIdx.x==0){
    int o=0;
    for(int l=0;l<NLEV;l++){ ints[32+l]=o; ints[64+l]=o; o+=ints[l]; }
    ints[32+NLEV]=o;
  }
}

// Two-pass per-block counting sort of nodes by level.
__global__ void k_build(const int* fl, int N, int* ints,
                        int* node_list, int* node_rank){
  __shared__ int h[16], base[16];
  int tid = threadIdx.x;
  int nchunk = (N + gridDim.x - 1)/gridDim.x;
  int lo = blockIdx.x*nchunk;
  int hi = lo + nchunk; if(hi>N) hi=N;
  if(tid<16) h[tid]=0;
  __syncthreads();
  for(int j=lo+tid; j<hi; j+=blockDim.x) atomicAdd(&h[fl[j]],1);
  __syncthreads();
  if(tid<16){ base[tid] = h[tid] ? atomicAdd(&ints[64+tid], h[tid]) : 0; h[tid]=0; }
  __syncthreads();
  for(int j=lo+tid; j<hi; j+=blockDim.x){
    int lev = fl[j];
    int pos = base[lev] + atomicAdd(&h[lev],1);
    node_list[pos]=j;
    node_rank[j]=pos-ints[32+lev];
  }
}

// ---------------- indegree histogram over permuted node positions ----------------
__global__ void k_indeg(const int* ei, const int* fl, const int* node_rank,
                        const int* ints, int* indeg, int E){
  int i = blockIdx.x*blockDim.x+threadIdx.x;
  int stride = gridDim.x*blockDim.x;
  for(int e=i;e<E;e+=stride){
    int tg = ei[E+e];
    int p = ints[32+fl[tg]] + node_rank[tg];
    atomicAdd(&indeg[p],1);
  }
}

// ---------------- hierarchical exclusive scan of indeg -> row_ptr ----------------
__global__ void k_scan_a(const int* indeg, int* bsum, int N){
  __shared__ int ts[256];
  int b=blockIdx.x, t=threadIdx.x;
  int base=b*SCAN_CHUNK+t*8; int s=0;
  for(int j=0;j<8;j++){ int idx=base+j; if(idx<N) s+=indeg[idx]; }
  ts[t]=s; __syncthreads();
  for(int off=128;off>0;off>>=1){ if(t<off) ts[t]+=ts[t+off]; __syncthreads(); }
  if(t==0) bsum[b]=ts[0];
}
__global__ void k_scan_b(int* bsum, int nb){
  __shared__ int ls[256];
  int t=threadIdx.x;
  int v = (t<nb)? bsum[t]:0; ls[t]=v; __syncthreads();
  for(int off=1;off<256;off<<=1){
    int add = (t>=off)? ls[t-off]:0;
    __syncthreads();
    ls[t]+=add;
    __syncthreads();
  }
  if(t<nb) bsum[t] = ls[t]-v;   // exclusive
}
__global__ void k_scan_c(const int* indeg, const int* bsum, int* row_ptr, int N){
  __shared__ int ts[256];
  int b=blockIdx.x, t=threadIdx.x;
  int base=b*SCAN_CHUNK+t*8;
  int v[8]; int s=0;
  for(int j=0;j<8;j++){ int idx=base+j; v[j]=(idx<N)?indeg[idx]:0; s+=v[j]; }
  ts[t]=s; __syncthreads();
  for(int off=1;off<256;off<<=1){
    int add = (t>=off)? ts[t-off]:0;
    __syncthreads();
    ts[t]+=add;
    __syncthreads();
  }
  int excl = bsum[b] + ((t>0)? ts[t-1]:0);
  for(int j=0;j<8;j++){ int idx=base+j; if(idx<N) row_ptr[idx]=excl; excl+=v[j]; }
}

// ---------------- place edges into CSR, packing source level into bits 27+ -------
__global__ void k_place(const int* ei, const int* fl, const int* node_rank,
                        const int* ints, const int* row_ptr, int* fill,
                        int* edge_src, int E){
  int i = blockIdx.x*blockDim.x+threadIdx.x;
  int stride = gridDim.x*blockDim.x;
  for(int e=i;e<E;e+=stride){
    int s  = ei[e];
    int tg = ei[E+e];
    int p = ints[32+fl[tg]] + node_rank[tg];
    int slot = atomicAdd(&fill[p],1);
    edge_src[row_ptr[p]+slot] = s | (fl[s]<<27);
  }
}

// ================= persistent all-levels kernel =================
// 256 blocks x 512 threads, 1 block/CU. Weights live in VGPRs per wave.
// LDS layout (51200 B):
//   A    @0      : Ahi [32][AS] u16 (10752) | Alo (10752)      -> 21504
//   H    alias A : Hhi [32][HS] u16 (8704)  | Hlo (8704)       -> 17408
//   tst  alias A : [32][128] f32 (16384)
//   z1l  @21504  : [32][33] f32 (4224)
//   z2l  @25728  : [32][33] f32 (4224)
//   w2t  @29952  : [32][33] f32 transposed (4224)
//   w3l  @34176  : 32 f32 (128)
//   w1t  @34304  : [128][33] f32 transposed (16896)
__global__ __launch_bounds__(BLK,2) void k_levels(
    const float* __restrict__ x, const int* __restrict__ node_list,
    const int* __restrict__ row_ptr, const int* __restrict__ indeg,
    const int* __restrict__ edge_src,
    float* __restrict__ tbuf,
    const unsigned short* __restrict__ wih_h, const unsigned short* __restrict__ wih_l,
    const unsigned short* __restrict__ agg_h, const unsigned short* __restrict__ agg_l,
    const float* __restrict__ b_ih, const float* __restrict__ agg_b,
    const float* __restrict__ w1, const float* __restrict__ b1,
    const float* __restrict__ w2, const float* __restrict__ b2,
    const float* __restrict__ w3, const float* __restrict__ b3,
    const float* __restrict__ consts, float* __restrict__ out,
    int* ints, int N)
{
  __shared__ __align__(16) unsigned char smem[51200];
  unsigned short* Ahi = (unsigned short*)smem;
  unsigned short* Alo = (unsigned short*)(smem + 10752);
  unsigned short* Hhi = (unsigned short*)smem;
  unsigned short* Hlo = (unsigned short*)(smem + 8704);
  float* tst = (float*)smem;
  float* z1l = (float*)(smem + 21504);
  float* z2l = (float*)(smem + 25728);
  float* w2t = (float*)(smem + 29952);
  float* w3l = (float*)(smem + 34176);
  float* w1t = (float*)(smem + 34304);

  int tid = threadIdx.x;
  int wv = tid>>6, ln = tid&63, lr = ln&15, lq = ln>>4;
  int cgo = tid&15, nd = tid>>4;   // gather: 16 thr/node, 8 dims each
  int d = wv*16 + lr;              // this lane's output dim

  // ---- persistent weight fragments ----
  short8_t wfh[15], wfl[15];
  #pragma unroll
  for(int g=0;g<3;g++)
    #pragma unroll
    for(int kk=0;kk<5;kk++){
      long long ro = (long long)(g*128 + d)*KP + kk*32 + lq*8;
      wfh[g*5+kk] = *(const short8_t*)&wih_h[ro];
      wfl[g*5+kk] = *(const short8_t*)&wih_l[ro];
    }
  short8_t agh[4], agl[4];
  #pragma unroll
  for(int kk=0;kk<4;kk++){
    int ro = d*DHID + kk*32 + lq*8;
    agh[kk] = *(const short8_t*)&agg_h[ro];
    agl[kk] = *(const short8_t*)&agg_l[ro];
  }
  float ghr=consts[256+d], ghz=consts[384+d], ghn=consts[512+d], h0c=consts[d];
  float bir=b_ih[d], biz=b_ih[128+d], bin_=b_ih[256+d], ab2=agg_b[d];
  f32x4 ti2a, ti2b;
  { const f32x4* c4=(const f32x4*)(consts+128); ti2a=c4[cgo*2]; ti2b=c4[cgo*2+1]; }

  // ---- stage small fp32 weights (transposed) ----
  for(int idx=tid; idx<4096; idx+=BLK){ int j=idx>>7, k=idx&127; w1t[k*33+j]=w1[idx]; }
  for(int idx=tid; idx<1024; idx+=BLK){ int j=idx>>5, k=idx&31;  w2t[k*33+j]=w2[idx]; }
  if(tid<32) w3l[tid]=w3[tid];

  // ---- out = c0 everywhere ----
  float c0 = consts[640];
  for(int j=blockIdx.x*BLK+tid; j<N; j+=GRID*BLK) out[j]=c0;

  int* bcnt  = &ints[200];
  int* bsen  = &ints[201];
  int nb = gridDim.x;
  int bp = 0;
  grid_barrier(bcnt,bsen,nb,++bp);

  for(int l=1;l<NLEV;l++){
    int cnt  = ints[l];
    int base = ints[32+l];
    int tiles = (cnt+31)>>5;
    for(int tile = blockIdx.x; tile < tiles; tile += gridDim.x){
      int n0 = tile*32;

      // ---- phase 0: gather msg (fp32) -> bf16 hi/lo into A ----
      {
        f32x4 a0={0.f,0.f,0.f,0.f}, a1={0.f,0.f,0.f,0.f};
        int gi = n0+nd;
        if(gi<cnt){
          int p = base+gi;
          int r0 = row_ptr[p], deg = indeg[p];
          const f32x4* t4 = (const f32x4*)tbuf;
          for(int e=0;e<deg;e++){
            int pk = edge_src[r0+e];
            int fls = ((unsigned)pk)>>27;
            int s = pk & 0x07FFFFFF;
            if(fls>=1 && fls<l){
              const f32x4* srcp = t4 + ((long long)s*32 + cgo*2);
              a0 += srcp[0]; a1 += srcp[1];
            } else {
              a0 += ti2a; a1 += ti2b;
            }
          }
        }
        short8_t hv, lv;
        #pragma unroll
        for(int j=0;j<8;j++){
          float v = (j<4)? a0[j] : a1[j-4];
          unsigned short h = f2bf(v);
          hv[j]=(short)h; lv[j]=(short)f2bf(v-bf2f(h));
        }
        *(short8_t*)&Ahi[nd*AS + cgo*8] = hv;
        *(short8_t*)&Alo[nd*AS + cgo*8] = lv;
      }
      // x into cols 128..143, zero cols 144..159
      if(tid<128){
        int i = tid>>2, j = tid&3;
        int gi = n0+i;
        float4 xv = make_float4(0.f,0.f,0.f,0.f);
        if(gi<cnt) xv = ((const float4*)x)[node_list[base+gi]*4 + j];
        float vv[4]={xv.x,xv.y,xv.z,xv.w};
        short hs[4], ls[4];
        #pragma unroll
        for(int q=0;q<4;q++){
          unsigned short h=f2bf(vv[q]); hs[q]=(short)h; ls[q]=(short)f2bf(vv[q]-bf2f(h));
        }
        int cb = 128+j*4;
        #pragma unroll
        for(int q=0;q<4;q++){ Ahi[i*AS+cb+q]=hs[q]; Alo[i*AS+cb+q]=ls[q]; }
        #pragma unroll
        for(int q=0;q<4;q++){ Ahi[i*AS+144+j*4+q]=0; Alo[i*AS+144+j*4+q]=0; }
      }
      __syncthreads();   // sync1: A ready

      // ---- phase 1: GEMM1 (bf16x3 MFMA, weights in regs) ----
      f32x4 Ar[2],Az[2],An[2];
      #pragma unroll
      for(int m=0;m<2;m++){
        Ar[m]=(f32x4){bir,bir,bir,bir};
        Az[m]=(f32x4){biz,biz,biz,biz};
        An[m]=(f32x4){bin_,bin_,bin_,bin_};
      }
      #pragma unroll
      for(int kk=0;kk<5;kk++){
        short8_t ah[2], al[2];
        #pragma unroll
        for(int m=0;m<2;m++){
          int off = (m*16+lr)*AS + kk*32 + lq*8;
          ah[m]=*(const short8_t*)&Ahi[off];
          al[m]=*(const short8_t*)&Alo[off];
        }
        #pragma unroll
        for(int m=0;m<2;m++){
          Ar[m]=__builtin_amdgcn_mfma_f32_16x16x32_bf16(ah[m],wfh[kk],   Ar[m],0,0,0);
          Ar[m]=__builtin_amdgcn_mfma_f32_16x16x32_bf16(ah[m],wfl[kk],   Ar[m],0,0,0);
          Ar[m]=__builtin_amdgcn_mfma_f32_16x16x32_bf16(al[m],wfh[kk],   Ar[m],0,0,0);
          Az[m]=__builtin_amdgcn_mfma_f32_16x16x32_bf16(ah[m],wfh[5+kk], Az[m],0,0,0);
          Az[m]=__builtin_amdgcn_mfma_f32_16x16x32_bf16(ah[m],wfl[5+kk], Az[m],0,0,0);
          Az[m]=__builtin_amdgcn_mfma_f32_16x16x32_bf16(al[m],wfh[5+kk], Az[m],0,0,0);
          An[m]=__builtin_amdgcn_mfma_f32_16x16x32_bf16(ah[m],wfh[10+kk],An[m],0,0,0);
          An[m]=__builtin_amdgcn_mfma_f32_16x16x32_bf16(ah[m],wfl[10+kk],An[m],0,0,0);
          An[m]=__builtin_amdgcn_mfma_f32_16x16x32_bf16(al[m],wfh[10+kk],An[m],0,0,0);
        }
      }
      __syncthreads();   // sync2: all A reads done, H may overwrite

      // ---- phase 2: GRU gates -> H (bf16 hi/lo over A region) ----
      #pragma unroll
      for(int m=0;m<2;m++){
        #pragma unroll
        for(int j=0;j<4;j++){
          float r = sigmoidf_(Ar[m][j] + ghr);
          float z = sigmoidf_(Az[m][j] + ghz);
          float n = tanhf_(An[m][j] + r*ghn);
          float h = (1.f-z)*n + z*h0c;
          int node = m*16 + lq*4 + j;
          unsigned short hb = f2bf(h);
          Hhi[node*HS + d] = hb;
          Hlo[node*HS + d] = f2bf(h - bf2f(hb));
        }
      }
      __syncthreads();   // sync3: H ready

      // ---- phase 3: GEMM2 (MFMA) + MLP1 (VALU) ----
      f32x4 T[2];
      #pragma unroll
      for(int m=0;m<2;m++) T[m]=(f32x4){ab2,ab2,ab2,ab2};
      #pragma unroll
      for(int kk=0;kk<4;kk++){
        short8_t hh[2], hl2[2];
        #pragma unroll
        for(int m=0;m<2;m++){
          int off = (m*16+lr)*HS + kk*32 + lq*8;
          hh[m]=*(const short8_t*)&Hhi[off];
          hl2[m]=*(const short8_t*)&Hlo[off];
        }
        #pragma unroll
        for(int m=0;m<2;m++){
          T[m]=__builtin_amdgcn_mfma_f32_16x16x32_bf16(hh[m], agh[kk],T[m],0,0,0);
          T[m]=__builtin_amdgcn_mfma_f32_16x16x32_bf16(hh[m], agl[kk],T[m],0,0,0);
          T[m]=__builtin_amdgcn_mfma_f32_16x16x32_bf16(hl2[m],agh[kk],T[m],0,0,0);
        }
      }
      {
        int ndl = tid>>4, jo = (tid&15)*2;
        float s0=b1[jo], s1=b1[jo+1];
        for(int k0=0;k0<128;k0+=8){
          short8_t hh8 = *(const short8_t*)&Hhi[ndl*HS+k0];
          short8_t hl8 = *(const short8_t*)&Hlo[ndl*HS+k0];
          #pragma unroll
          for(int kk=0;kk<8;kk++){
            float hvv = bf2f((unsigned short)hh8[kk]) + bf2f((unsigned short)hl8[kk]);
            float w1a = w1t[(k0+kk)*33+jo];
            float w1b = w1t[(k0+kk)*33+jo+1];
            s0 += hvv*w1a; s1 += hvv*w1b;
          }
        }
        z1l[ndl*33+jo]   = fmaxf(s0,0.f);
        z1l[ndl*33+jo+1] = fmaxf(s1,0.f);
      }
      __syncthreads();   // sync4: H reads done, tst may overwrite; z1 ready

      // ---- phase 4: stage t into LDS (fp32) + MLP2 ----
      #pragma unroll
      for(int m=0;m<2;m++){
        #pragma unroll
        for(int j=0;j<4;j++){
          int node = m*16 + lq*4 + j;
          tst[node*128 + d] = T[m][j];
        }
      }
      {
        int ndl = tid>>4, jo = (tid&15)*2;
        float s0=b2[jo], s1=b2[jo+1];
        #pragma unroll 8
        for(int k=0;k<32;k++){
          float zv = z1l[ndl*33+k];
          s0 += zv*w2t[k*33+jo];
          s1 += zv*w2t[k*33+jo+1];
        }
        z2l[ndl*33+jo]   = fmaxf(s0,0.f);
        z2l[ndl*33+jo+1] = fmaxf(s1,0.f);
      }
      __syncthreads();   // sync5: tst + z2 ready

      // ---- phase 5: coalesced t store + out store ----
      {
        int nd2 = tid>>4, q = tid&15;
        int gi = n0+nd2;
        if(gi<cnt){
          long long v = node_list[base+gi];
          float4 v0 = *(const float4*)&tst[nd2*128 + q*8];
          float4 v1 = *(const float4*)&tst[nd2*128 + q*8 + 4];
          ((float4*)tbuf)[v*32 + q*2]   = v0;
          ((float4*)tbuf)[v*32 + q*2+1] = v1;
        }
      }
      if(tid<32){
        int gi = n0+tid;
        if(gi<cnt){
          float s = b3[0];
          #pragma unroll 8
          for(int k=0;k<32;k++) s += z2l[tid*33+k]*w3l[k];
          out[node_list[base+gi]] = s;
        }
      }
      __syncthreads();   // sync6: protect LDS before next tile
    }
    if(l < NLEV-1) grid_barrier(bcnt,bsen,nb,++bp);
  }
}

extern "C" void kernel_launch(void* const* d_in, const int* in_sizes, int n_in,
                              void* d_out, int out_size, void* d_ws, size_t ws_size,
                              hipStream_t stream){
  const float* x     = (const float*)d_in[0];
  const int*   ei    = (const int*)  d_in[1];
  const int*   fl    = (const int*)  d_in[2];
  const float* emd_w = (const float*)d_in[4];
  const float* emd_b = (const float*)d_in[5];
  const float* agg_w = (const float*)d_in[6];
  const float* agg_b = (const float*)d_in[7];
  const float* w_ih  = (const float*)d_in[8];
  const float* w_hh  = (const float*)d_in[9];
  const float* b_ih  = (const float*)d_in[10];
  const float* b_hh  = (const float*)d_in[11];
  const float* w1    = (const float*)d_in[12];
  const float* b1    = (const float*)d_in[13];
  const float* w2    = (const float*)d_in[14];
  const float* b2    = (const float*)d_in[15];
  const float* w3    = (const float*)d_in[16];
  const float* b3    = (const float*)d_in[17];
  float* out = (float*)d_out;

  int N = in_sizes[2];
  int E = in_sizes[1]/2;
  int nb = (N + SCAN_CHUNK - 1)/SCAN_CHUNK;

  char* ws = (char*)d_ws;
  float* consts   = (float*)ws;                    // 4 KiB
  int*   ints     = (int*)(ws + 4096);             // 4 KiB (incl. barrier @200,201)
  int*   node_list= (int*)(ws + 8192);
  int*   node_rank= node_list + N;
  int*   indeg    = node_rank + N;
  int*   row_ptr  = indeg + N;
  int*   fill     = row_ptr + N;
  int*   bsum     = fill + N;                      // 1024 block sums
  int*   edge_src = bsum + 1024;                   // E ints (level in bits 27+)
  size_t off0 = 8192 + ((size_t)5*N + 1024 + (size_t)E)*4;
  off0 = (off0 + 255) & ~(size_t)255;
  unsigned short* wih_h = (unsigned short*)(ws + off0);       // 384*160
  unsigned short* wih_l = wih_h + G3*KP;
  unsigned short* agg_h = wih_l + G3*KP;                      // 128*128
  unsigned short* agg_l = agg_h + DHID*DHID;
  size_t off1 = off0 + (size_t)(2*G3*KP + 2*DHID*DHID)*2;
  off1 = (off1 + 255) & ~(size_t)255;
  float* tbuf = (float*)(ws + off1);               // N*128 floats, never pre-initialized
  size_t need = off1 + (size_t)N*128*4;
  if(ws_size < need) return;

  k_zero0  <<<512,256,0,stream>>>(ints, indeg, fill, N);
  k_init   <<<1,128,0,stream>>>(emd_w,emd_b,agg_w,agg_b,w_hh,b_hh,w1,b1,w2,b2,w3,b3,consts);
  k_wprep  <<<256,256,0,stream>>>(w_ih,agg_w,wih_h,wih_l,agg_h,agg_l);
  k_count  <<<512,256,0,stream>>>(fl,N,ints);
  k_prefix <<<1,1,0,stream>>>(ints);
  k_build  <<<512,256,0,stream>>>(fl,N,ints,node_list,node_rank);
  k_indeg  <<<1024,256,0,stream>>>(ei,fl,node_rank,ints,indeg,E);
  k_scan_a <<<nb,256,0,stream>>>(indeg,bsum,N);
  k_scan_b <<<1,256,0,stream>>>(bsum,nb);
  k_scan_c <<<nb,256,0,stream>>>(indeg,bsum,row_ptr,N);
  k_place  <<<1024,256,0,stream>>>(ei,fl,node_rank,ints,row_ptr,fill,edge_src,E);
  k_levels <<<GRID,BLK,0,stream>>>(x,node_list,row_ptr,indeg,edge_src,tbuf,
                                   wih_h,wih_l,agg_h,agg_l,
                                   b_ih,agg_b,w1,b1,w2,b2,w3,b3,
                                   consts,out,ints,N);
}